// Round 5
// baseline (286.052 us; speedup 1.0000x reference)
//
#include <hip/hip_runtime.h>
#include <hip/hip_bf16.h>
#include <stdint.h>

typedef __bf16 bf16_t;
typedef __bf16 bf16x8 __attribute__((ext_vector_type(8)));
typedef float  f32x4  __attribute__((ext_vector_type(4)));
typedef float  f32x16 __attribute__((ext_vector_type(16)));

#define K_DIM 4096
#define N_DIM 4096

// ---------------------------------------------------------------------------
// Kernel 1: x fp32 -> bf16
// ---------------------------------------------------------------------------
__global__ __launch_bounds__(256) void convert_x_kernel(const float* __restrict__ x,
                                                        bf16_t* __restrict__ xb) {
    const long long i = ((long long)blockIdx.x * blockDim.x + threadIdx.x) * 8;
    float4 a = *(const float4*)(x + i);
    float4 b = *(const float4*)(x + i + 4);
    bf16x8 o;
    o[0] = (bf16_t)a.x; o[1] = (bf16_t)a.y; o[2] = (bf16_t)a.z; o[3] = (bf16_t)a.w;
    o[4] = (bf16_t)b.x; o[5] = (bf16_t)b.y; o[6] = (bf16_t)b.z; o[7] = (bf16_t)b.w;
    *(bf16x8*)(xb + i) = o;
}

// ---------------------------------------------------------------------------
// Kernel 2: weight row -> sign (bf16, exact) + per-row mean|w| (fp32)
// ---------------------------------------------------------------------------
__device__ __forceinline__ bf16_t sgn_bf16(float f) {
    return (bf16_t)((f > 0.f) ? 1.f : ((f < 0.f) ? -1.f : 0.f));
}

__global__ __launch_bounds__(256) void convert_w_kernel(const float* __restrict__ w,
                                                        bf16_t* __restrict__ wb,
                                                        float* __restrict__ s) {
    const int row = blockIdx.x;
    const int tid = threadIdx.x;
    const float* wr = w + (long long)row * K_DIM;
    bf16_t* wbr = wb + (long long)row * K_DIM;
    const int off = tid * 16;

    float sum = 0.f;
    bf16x8 o0, o1;
    #pragma unroll
    for (int j = 0; j < 2; ++j) {
        float4 v = *(const float4*)(wr + off + j * 4);
        sum += fabsf(v.x) + fabsf(v.y) + fabsf(v.z) + fabsf(v.w);
        o0[j * 4 + 0] = sgn_bf16(v.x); o0[j * 4 + 1] = sgn_bf16(v.y);
        o0[j * 4 + 2] = sgn_bf16(v.z); o0[j * 4 + 3] = sgn_bf16(v.w);
    }
    #pragma unroll
    for (int j = 0; j < 2; ++j) {
        float4 v = *(const float4*)(wr + off + 8 + j * 4);
        sum += fabsf(v.x) + fabsf(v.y) + fabsf(v.z) + fabsf(v.w);
        o1[j * 4 + 0] = sgn_bf16(v.x); o1[j * 4 + 1] = sgn_bf16(v.y);
        o1[j * 4 + 2] = sgn_bf16(v.z); o1[j * 4 + 3] = sgn_bf16(v.w);
    }
    *(bf16x8*)(wbr + off)     = o0;
    *(bf16x8*)(wbr + off + 8) = o1;

    #pragma unroll
    for (int d = 32; d > 0; d >>= 1) sum += __shfl_down(sum, d);
    __shared__ float red[4];
    const int lane = tid & 63, wid = tid >> 6;
    if (lane == 0) red[wid] = sum;
    __syncthreads();
    if (tid == 0) s[row] = (red[0] + red[1] + red[2] + red[3]) * (1.0f / (float)K_DIM);
}

// ===========================================================================
// 256x256 GEMM, k-step-pipelined with 32x32x16 MFMA.
// Per K-tile t (BK=64): 4 phases = 4 k-steps of 16. Phase p:
//   { ds_read frags k(p+1) | stage | bar | MFMA k(p) | bar }
// MFMA never depends on same-phase reads -> LDS pipe overlaps MFMA pipe.
// Frag double-buffer X/Y (24 VGPR each, statically swapped) keeps register
// footprint ~200 (round-4's whole-phase prefetch spilled at ~224+).
// Staging: Bh(t+1)@P0/P1 into next buf; Ah(t+2)@P3 into CURRENT A buf
// (freed after P2's k3 read). vmcnt(4) before P3's barrier: in-flight then =
// {Ah(t+1) x4, Bh(t+1) x4, Ah(t+2) x4} = 12 -> drains oldest 8 = tile t+1
// exactly; P3 then reads k0(t+1) from the other buffer.
// ===========================================================================
struct SOp { const bf16_t* g; int row0; int kt; bf16_t* l; };

__device__ __forceinline__ void stage_half(const SOp s, int wid, int lane) {
    const int r  = s.row0 + wid * 16 + (lane >> 3);
    const int ce = s.kt + (((lane & 7) ^ (lane >> 3)) << 3);  // pre-swizzled src col
    const bf16_t* src0 = s.g + (long long)r * K_DIM + ce;
    __builtin_amdgcn_global_load_lds(
        (const __attribute__((address_space(1))) void*)src0,
        (__attribute__((address_space(3))) void*)(s.l + wid * 1024), 16, 0, 0);
    __builtin_amdgcn_global_load_lds(
        (const __attribute__((address_space(1))) void*)(src0 + (long long)8 * K_DIM),
        (__attribute__((address_space(3))) void*)(s.l + wid * 1024 + 512), 16, 0, 0);
}

__device__ __forceinline__ bf16x8 ldsr(const bf16_t* t, int row, int kbyte) {
    const int cb = kbyte ^ ((row & 7) << 4);
    return *(const bf16x8*)((const char*)t + row * 128 + cb);
}

// read one k-step's fragments (32x32x16 operand layout: row=lane&31,
// k = (lane>>5)*8 + i, i.e. 16B at byte col ks*32 + (lane>>5)*16)
__device__ __forceinline__ void read_k32(bf16x8 (&ra)[4], bf16x8 (&rb)[2],
                                         const bf16_t* tA, const bf16_t* tB,
                                         int wm, int wn, int lane, int ks) {
    const int l31 = lane & 31;
    const int kbyte = ks * 32 + ((lane >> 5) << 4);
    #pragma unroll
    for (int mi = 0; mi < 4; ++mi)
        ra[mi] = ldsr(tA, wm * 128 + mi * 32 + l31, kbyte);
    #pragma unroll
    for (int ni = 0; ni < 2; ++ni)
        rb[ni] = ldsr(tB, wn * 64 + ni * 32 + l31, kbyte);
}

__device__ __forceinline__ void mfma_k(f32x16 (&acc)[4][2],
                                       const bf16x8 (&ra)[4], const bf16x8 (&rb)[2]) {
    #pragma unroll
    for (int mi = 0; mi < 4; ++mi)
        #pragma unroll
        for (int ni = 0; ni < 2; ++ni)
            acc[mi][ni] = __builtin_amdgcn_mfma_f32_32x32x16_bf16(
                ra[mi], rb[ni], acc[mi][ni], 0, 0, 0);
}

// SB: stage Bh(t+1)@P0/P1 into nB. SA: stage Ah(t+2)@P3 into tA.
// WN: 4 steady / 0 drain / -1 none. RA: read k0(t+1)@P3 from nA/nB.
template<bool SB, bool SA, int WN, bool RA>
__device__ __forceinline__ void ktile(bf16_t* tA, bf16_t* tB, bf16_t* nA, bf16_t* nB,
                                      const bf16_t* gA, const bf16_t* gB, int kt,
                                      bf16x8 (&xa)[4], bf16x8 (&xb)[2],
                                      bf16x8 (&ya)[4], bf16x8 (&yb)[2],
                                      f32x16 (&acc)[4][2],
                                      int wm, int wn, int wid, int lane)
{
    // ---- P0: read Y<-k1 | stage Bh0(t+1) | MFMA X (k0)
    read_k32(ya, yb, tA, tB, wm, wn, lane, 1);
    if constexpr (SB) stage_half({gB, 0, kt + 64, nB}, wid, lane);
    __builtin_amdgcn_s_barrier();
    __builtin_amdgcn_s_setprio(1);
    mfma_k(acc, xa, xb);
    __builtin_amdgcn_s_setprio(0);
    __builtin_amdgcn_s_barrier();

    // ---- P1: read X<-k2 | stage Bh1(t+1) | MFMA Y (k1)
    read_k32(xa, xb, tA, tB, wm, wn, lane, 2);
    if constexpr (SB) stage_half({gB, 128, kt + 64, nB + 8192}, wid, lane);
    __builtin_amdgcn_s_barrier();
    __builtin_amdgcn_s_setprio(1);
    mfma_k(acc, ya, yb);
    __builtin_amdgcn_s_setprio(0);
    __builtin_amdgcn_s_barrier();

    // ---- P2: read Y<-k3 | MFMA X (k2)
    read_k32(ya, yb, tA, tB, wm, wn, lane, 3);
    __builtin_amdgcn_s_barrier();
    __builtin_amdgcn_s_setprio(1);
    mfma_k(acc, xa, xb);
    __builtin_amdgcn_s_setprio(0);
    __builtin_amdgcn_s_barrier();

    // ---- P3: stage Ah(t+2) into tA (k3 of tA already read at P2);
    //          vmcnt -> tile t+1 landed; bar; read X<-k0(t+1); MFMA Y (k3)
    if constexpr (SA) {
        stage_half({gA, 0,   kt + 128, tA}, wid, lane);
        stage_half({gA, 128, kt + 128, tA + 8192}, wid, lane);
    }
    if constexpr (WN == 4)      asm volatile("s_waitcnt vmcnt(4)" ::: "memory");
    else if constexpr (WN == 0) asm volatile("s_waitcnt vmcnt(0)" ::: "memory");
    __builtin_amdgcn_s_barrier();
    if constexpr (RA) read_k32(xa, xb, nA, nB, wm, wn, lane, 0);
    __builtin_amdgcn_s_setprio(1);
    mfma_k(acc, ya, yb);
    __builtin_amdgcn_s_setprio(0);
    __builtin_amdgcn_s_barrier();
}

__global__ __launch_bounds__(512, 2) void bitlinear_gemm256(
    const bf16_t* __restrict__ A, const bf16_t* __restrict__ B,
    const float* __restrict__ scale, float* __restrict__ C, int M)
{
    extern __shared__ bf16_t smem[];
    bf16_t* As0 = smem;                 // [256][64] each
    bf16_t* As1 = smem + 16384;
    bf16_t* Bs0 = smem + 32768;
    bf16_t* Bs1 = smem + 49152;

    const int tid = threadIdx.x, lane = tid & 63, wid = tid >> 6;
    const int wm = wid >> 2, wn = wid & 3;

    // T1: bijective XCD swizzle (grid % 8 == 0 guaranteed by launcher)
    const int nbid = (int)blockIdx.x;
    const int cpx  = (int)gridDim.x >> 3;
    const int swz  = (nbid & 7) * cpx + (nbid >> 3);
    const int ntn  = N_DIM / 256;       // 16
    const int tm = swz / ntn, tn = swz % ntn;

    const bf16_t* gA = A + (long long)tm * 256 * K_DIM;
    const bf16_t* gB = B + (long long)tn * 256 * K_DIM;

    f32x16 acc[4][2];
    #pragma unroll
    for (int i = 0; i < 4; ++i)
        #pragma unroll
        for (int j = 0; j < 2; ++j)
            #pragma unroll
            for (int r = 0; r < 16; ++r) acc[i][j][r] = 0.f;

    // prologue: tile0 all 4 halves + Ah(1) (plays the SA@P3(-1) role);
    // vmcnt(4) drains tile0's 8, leaves Ah(1)'s 4 in flight.
    stage_half({gA,   0,  0, As0},        wid, lane);
    stage_half({gA, 128,  0, As0 + 8192}, wid, lane);
    stage_half({gB,   0,  0, Bs0},        wid, lane);
    stage_half({gB, 128,  0, Bs0 + 8192}, wid, lane);
    stage_half({gA,   0, 64, As1},        wid, lane);
    stage_half({gA, 128, 64, As1 + 8192}, wid, lane);
    asm volatile("s_waitcnt vmcnt(4)" ::: "memory");
    __builtin_amdgcn_s_barrier();

    bf16x8 xa[4], xb[2], ya[4], yb[2];
    read_k32(xa, xb, As0, Bs0, wm, wn, lane, 0);

    // t=0..61 steady (31 pairs)
    #pragma unroll 1
    for (int i = 0; i < 31; ++i) {
        ktile<true, true, 4, true>(As0, Bs0, As1, Bs1, gA, gB, (2 * i) * 64,
                                   xa, xb, ya, yb, acc, wm, wn, wid, lane);
        ktile<true, true, 4, true>(As1, Bs1, As0, Bs0, gA, gB, (2 * i + 1) * 64,
                                   xa, xb, ya, yb, acc, wm, wn, wid, lane);
    }
    // t=62 (buf0): stage Bh(63); no Ah(64); drain; read k0(63)
    ktile<true, false, 0, true>(As0, Bs0, As1, Bs1, gA, gB, 62 * 64,
                                xa, xb, ya, yb, acc, wm, wn, wid, lane);
    // t=63 (buf1): plain compute
    ktile<false, false, -1, false>(As1, Bs1, As0, Bs0, gA, gB, 63 * 64,
                                   xa, xb, ya, yb, acc, wm, wn, wid, lane);

    // epilogue: scale + store. 32x32 C/D: col=lane&31,
    // row = (reg&3) + 8*(reg>>2) + 4*(lane>>5)   [m74/m101 verified]
    const long long m0 = (long long)tm * 256 + wm * 128;
    const long long n0 = (long long)tn * 256 + wn * 64;
    float sc[2];
    #pragma unroll
    for (int ni = 0; ni < 2; ++ni) sc[ni] = scale[n0 + ni * 32 + (lane & 31)];
    #pragma unroll
    for (int mi = 0; mi < 4; ++mi) {
        #pragma unroll
        for (int ni = 0; ni < 2; ++ni) {
            const long long col = n0 + ni * 32 + (lane & 31);
            #pragma unroll
            for (int r = 0; r < 16; ++r) {
                const long long row = m0 + mi * 32 + (r & 3) + 8 * (r >> 2) + 4 * (lane >> 5);
                C[row * N_DIM + col] = acc[mi][ni][r] * sc[ni];
            }
        }
    }
}

// ---------------------------------------------------------------------------
// Proven round-1 128x128 GEMM — fallback path
// ---------------------------------------------------------------------------
__global__ __launch_bounds__(256) void bitlinear_gemm_kernel(
    const bf16_t* __restrict__ A, const bf16_t* __restrict__ B,
    const float* __restrict__ scale, float* __restrict__ C, int M)
{
    constexpr int BK = 64;
    __shared__ bf16_t As[128 * BK];
    __shared__ bf16_t Bs[128 * BK];

    const int tid  = threadIdx.x;
    const int lane = tid & 63;
    const int wid  = tid >> 6;
    const int wr   = wid >> 1;
    const int wc   = wid & 1;

    const int ntn = N_DIM / 128;
    const int tm  = blockIdx.x / ntn;
    const int tn  = blockIdx.x % ntn;
    const long long m0 = (long long)tm * 128;
    const long long n0 = (long long)tn * 128;

    const int srow = wid * 32 + (lane >> 3);
    const int scol = (lane & 7) * 8;
    const bf16_t* gA = A + (m0 + srow) * K_DIM + scol;
    const bf16_t* gB = B + (n0 + srow) * K_DIM + scol;
    bf16_t* lA = As + wid * 2048;
    bf16_t* lB = Bs + wid * 2048;

    const f32x4 zero = {0.f, 0.f, 0.f, 0.f};
    f32x4 acc[4][4];
    #pragma unroll
    for (int i = 0; i < 4; ++i)
        #pragma unroll
        for (int j = 0; j < 4; ++j) acc[i][j] = zero;

    for (int kt = 0; kt < K_DIM; kt += BK) {
        #pragma unroll
        for (int i = 0; i < 4; ++i)
            __builtin_amdgcn_global_load_lds(
                (const __attribute__((address_space(1))) void*)(gA + (long long)i * 8 * K_DIM + kt),
                (__attribute__((address_space(3))) void*)(lA + i * 512), 16, 0, 0);
        #pragma unroll
        for (int i = 0; i < 4; ++i)
            __builtin_amdgcn_global_load_lds(
                (const __attribute__((address_space(1))) void*)(gB + (long long)i * 8 * K_DIM + kt),
                (__attribute__((address_space(3))) void*)(lB + i * 512), 16, 0, 0);
        __syncthreads();

        #pragma unroll
        for (int kk = 0; kk < 2; ++kk) {
            const int kc = kk * 32 + (lane >> 4) * 8;
            bf16x8 af[4], bfr[4];
            #pragma unroll
            for (int mi = 0; mi < 4; ++mi)
                af[mi] = *(const bf16x8*)(As + (wr * 64 + mi * 16 + (lane & 15)) * BK + kc);
            #pragma unroll
            for (int ni = 0; ni < 4; ++ni)
                bfr[ni] = *(const bf16x8*)(Bs + (wc * 64 + ni * 16 + (lane & 15)) * BK + kc);
            #pragma unroll
            for (int mi = 0; mi < 4; ++mi)
                #pragma unroll
                for (int ni = 0; ni < 4; ++ni)
                    acc[mi][ni] = __builtin_amdgcn_mfma_f32_16x16x32_bf16(
                        af[mi], bfr[ni], acc[mi][ni], 0, 0, 0);
        }
        __syncthreads();
    }

    float sc[4];
    #pragma unroll
    for (int ni = 0; ni < 4; ++ni)
        sc[ni] = scale[n0 + wc * 64 + ni * 16 + (lane & 15)];
    #pragma unroll
    for (int mi = 0; mi < 4; ++mi) {
        const long long rowb = m0 + wr * 64 + mi * 16 + (lane >> 4) * 4;
        #pragma unroll
        for (int ni = 0; ni < 4; ++ni) {
            const long long col = n0 + wc * 64 + ni * 16 + (lane & 15);
            #pragma unroll
            for (int j = 0; j < 4; ++j)
                C[(rowb + j) * N_DIM + col] = acc[mi][ni][j] * sc[ni];
        }
    }
}

__global__ void bitlinear_naive_kernel(const float* __restrict__ x,
                                       const float* __restrict__ w,
                                       float* __restrict__ out, long long total) {
    const long long idx = (long long)blockIdx.x * blockDim.x + threadIdx.x;
    if (idx >= total) return;
    const long long m = idx / N_DIM;
    const long long o = idx % N_DIM;
    const float* xr = x + m * K_DIM;
    const float* wrow = w + o * K_DIM;
    float sum = 0.f, sa = 0.f;
    for (int k = 0; k < K_DIM; ++k) {
        float wv = wrow[k];
        sa += fabsf(wv);
        sum += xr[k] * ((wv > 0.f) ? 1.f : ((wv < 0.f) ? -1.f : 0.f));
    }
    out[idx] = sum * (sa * (1.0f / (float)K_DIM));
}

// ---------------------------------------------------------------------------
extern "C" void kernel_launch(void* const* d_in, const int* in_sizes, int n_in,
                              void* d_out, int out_size, void* d_ws, size_t ws_size,
                              hipStream_t stream) {
    const float* x = (const float*)d_in[0];
    const float* w = (const float*)d_in[1];
    float* out = (float*)d_out;

    const int M = in_sizes[0] / K_DIM;

    const size_t xb_bytes = (size_t)M * K_DIM * sizeof(bf16_t);
    const size_t wb_bytes = (size_t)N_DIM * K_DIM * sizeof(bf16_t);
    const size_t s_bytes  = (size_t)N_DIM * sizeof(float);

    if (ws_size < xb_bytes + wb_bytes + s_bytes || (M % 128) != 0) {
        const long long total = (long long)M * N_DIM;
        bitlinear_naive_kernel<<<(int)((total + 255) / 256), 256, 0, stream>>>(x, w, out, total);
        return;
    }

    bf16_t* xb = (bf16_t*)d_ws;
    bf16_t* wb = (bf16_t*)((char*)d_ws + xb_bytes);
    float*  s  = (float*)((char*)d_ws + xb_bytes + wb_bytes);

    convert_x_kernel<<<(M * (K_DIM / 8)) / 256, 256, 0, stream>>>(x, xb);
    convert_w_kernel<<<N_DIM, 256, 0, stream>>>(w, wb, s);

    bool use256 = (M % 256) == 0;
    if (use256) {
        hipError_t e = hipFuncSetAttribute((const void*)bitlinear_gemm256,
                                           hipFuncAttributeMaxDynamicSharedMemorySize,
                                           131072);
        if (e != hipSuccess) use256 = false;
    }
    if (use256) {
        const int grid = (M / 256) * (N_DIM / 256);   // 32*16 = 512, %8==0
        bitlinear_gemm256<<<grid, 512, 131072, stream>>>(xb, wb, s, out, M);
    } else {
        const int grid = (M / 128) * (N_DIM / 128);
        bitlinear_gemm_kernel<<<grid, 256, 0, stream>>>(xb, wb, s, out, M);
    }
}

// Round 6
// 185.377 us; speedup vs baseline: 1.5431x; 1.5431x over previous
//
#include <hip/hip_runtime.h>
#include <hip/hip_bf16.h>
#include <stdint.h>

typedef int  iv4   __attribute__((ext_vector_type(4)));   // 16 i8 operand / i32x4 acc
typedef float f32x4 __attribute__((ext_vector_type(4)));

#define K_DIM 4096
#define N_DIM 4096

// ---------------------------------------------------------------------------
// Kernel 1: x fp32 -> i8 with per-row scale sx[row] = rowmax/127.
// One block (256 thr) per row; 16 elems/thread held in registers across the
// max-reduce so the row is read once.
// ---------------------------------------------------------------------------
__global__ __launch_bounds__(256) void convert_x_i8(const float* __restrict__ x,
                                                    char* __restrict__ xq,
                                                    float* __restrict__ sx) {
    const int row = blockIdx.x;
    const int tid = threadIdx.x;
    const float* xr = x + (long long)row * K_DIM + tid * 16;

    float4 v0 = *(const float4*)(xr + 0);
    float4 v1 = *(const float4*)(xr + 4);
    float4 v2 = *(const float4*)(xr + 8);
    float4 v3 = *(const float4*)(xr + 12);

    float m = fabsf(v0.x);
    m = fmaxf(m, fabsf(v0.y)); m = fmaxf(m, fabsf(v0.z)); m = fmaxf(m, fabsf(v0.w));
    m = fmaxf(m, fabsf(v1.x)); m = fmaxf(m, fabsf(v1.y)); m = fmaxf(m, fabsf(v1.z)); m = fmaxf(m, fabsf(v1.w));
    m = fmaxf(m, fabsf(v2.x)); m = fmaxf(m, fabsf(v2.y)); m = fmaxf(m, fabsf(v2.z)); m = fmaxf(m, fabsf(v2.w));
    m = fmaxf(m, fabsf(v3.x)); m = fmaxf(m, fabsf(v3.y)); m = fmaxf(m, fabsf(v3.z)); m = fmaxf(m, fabsf(v3.w));

    #pragma unroll
    for (int d = 32; d > 0; d >>= 1) m = fmaxf(m, __shfl_xor(m, d));
    __shared__ float red[4];
    const int lane = tid & 63, wid = tid >> 6;
    if (lane == 0) red[wid] = m;
    __syncthreads();
    float rmax = fmaxf(fmaxf(red[0], red[1]), fmaxf(red[2], red[3]));
    rmax = fmaxf(rmax, 1e-20f);
    if (tid == 0) sx[row] = rmax * (1.0f / 127.0f);

    const float q = 127.0f / rmax;
    union { char c[16]; int4 v; } u;
    const float vals[16] = {v0.x, v0.y, v0.z, v0.w, v1.x, v1.y, v1.z, v1.w,
                            v2.x, v2.y, v2.z, v2.w, v3.x, v3.y, v3.z, v3.w};
    #pragma unroll
    for (int i = 0; i < 16; ++i) u.c[i] = (char)__float2int_rn(vals[i] * q);
    *(int4*)(xq + (long long)row * K_DIM + tid * 16) = u.v;
}

// ---------------------------------------------------------------------------
// Kernel 2: weight row -> sign (i8, exact) + per-row mean|w| (fp32)
// ---------------------------------------------------------------------------
__global__ __launch_bounds__(256) void convert_w_i8(const float* __restrict__ w,
                                                    char* __restrict__ wq,
                                                    float* __restrict__ sw) {
    const int row = blockIdx.x;
    const int tid = threadIdx.x;
    const float* wr = w + (long long)row * K_DIM + tid * 16;

    float sum = 0.f;
    union { char c[16]; int4 v; } u;
    #pragma unroll
    for (int j = 0; j < 4; ++j) {
        float4 v = *(const float4*)(wr + j * 4);
        sum += fabsf(v.x) + fabsf(v.y) + fabsf(v.z) + fabsf(v.w);
        u.c[j * 4 + 0] = (char)((v.x > 0.f) - (v.x < 0.f));
        u.c[j * 4 + 1] = (char)((v.y > 0.f) - (v.y < 0.f));
        u.c[j * 4 + 2] = (char)((v.z > 0.f) - (v.z < 0.f));
        u.c[j * 4 + 3] = (char)((v.w > 0.f) - (v.w < 0.f));
    }
    *(int4*)(wq + (long long)row * K_DIM + tid * 16) = u.v;

    #pragma unroll
    for (int d = 32; d > 0; d >>= 1) sum += __shfl_down(sum, d);
    __shared__ float red[4];
    const int lane = tid & 63, wid = tid >> 6;
    if (lane == 0) red[wid] = sum;
    __syncthreads();
    if (tid == 0) sw[row] = (red[0] + red[1] + red[2] + red[3]) * (1.0f / (float)K_DIM);
}

// ===========================================================================
// 256x256 i8 GEMM, exact clone of the verified round-2/3 sync structure
// (quadrant phases, stage-per-phase, counted vmcnt), rescaled for i8:
//   - K-tile = 64 i8 = 64 BYTES per row; one 16x16x64 MFMA covers full BK.
//   - per phase: q00 {read a0(4)+b0(2)} / q01 {b1(2)} / q10 {a1(4)} / q11 {}
//     8 MFMA each. EXACT i32 accumulation (signs are +-1).
//   - LDS row = 64B = 4 slots of 16B. Swizzle: slot' = slot ^ ((row>>1)&3);
//     (row&1) lands on byte-bit 6 naturally -> 8-lane read groups hit 8
//     distinct bank-spans (same conflict-free class as rounds 2-4).
//   - stage_half = ONE global_load_lds per wave (16 rows x 64B = 1024B);
//     4 stage ops per K-tile -> steady vmcnt(1) drains exactly tile t+1.
//   - LDS total 64 KiB (2 dbuf x (A 16K + B 16K)).
// ===========================================================================
struct SOp { const char* g; int row0; int kt; char* l; };

__device__ __forceinline__ void stage_half(const SOp s, int wid, int lane) {
    // lane -> row-in-instr lane>>2 (row&7 = (lane>>2)&7), slot lane&3.
    // pre-swizzled global source: srcslot = (lane&3) ^ g(row&7), g(r)=(r>>1)&3
    const int r      = s.row0 + wid * 16 + (lane >> 2);
    const int srcoff = s.kt + ((((lane & 3) ^ ((lane >> 3) & 3))) << 4);
    const char* src  = s.g + (long long)r * K_DIM + srcoff;
    __builtin_amdgcn_global_load_lds(
        (const __attribute__((address_space(1))) void*)src,
        (__attribute__((address_space(3))) void*)(s.l + wid * 1024), 16, 0, 0);
}

__device__ __forceinline__ iv4 ldsr(const char* t, int row, int c) {
    const int off = row * 64 + ((c ^ ((row >> 1) & 3)) << 4);
    return *(const iv4*)(t + off);
}

// frag reads: lane holds row = base + (lane&15), k-slot c = lane>>4 (16 i8)
__device__ __forceinline__ void read_a0(iv4 (&a)[4], const char* tA, int wm, int l15, int c) {
    #pragma unroll
    for (int mi = 0; mi < 4; ++mi) a[mi] = ldsr(tA, wm * 128 + mi * 16 + l15, c);
}
__device__ __forceinline__ void read_a1(iv4 (&a)[4], const char* tA, int wm, int l15, int c) {
    #pragma unroll
    for (int mi = 0; mi < 4; ++mi) a[mi] = ldsr(tA, wm * 128 + 64 + mi * 16 + l15, c);
}
__device__ __forceinline__ void read_b0(iv4 (&b)[2], const char* tB, int wn, int l15, int c) {
    #pragma unroll
    for (int ni = 0; ni < 2; ++ni) b[ni] = ldsr(tB, wn * 64 + ni * 16 + l15, c);
}
__device__ __forceinline__ void read_b1(iv4 (&b)[2], const char* tB, int wn, int l15, int c) {
    #pragma unroll
    for (int ni = 0; ni < 2; ++ni) b[ni] = ldsr(tB, wn * 64 + 32 + ni * 16 + l15, c);
}

// S0..S3: stage ops per phase. WN: 1 steady / 0 drain / -1 none(+no barrier).
template<bool S0, bool S1, bool S2, bool S3, int WN>
__device__ __forceinline__ void kgroup(const char* __restrict__ tA,
                                       const char* __restrict__ tB,
                                       SOp s0, SOp s1, SOp s2, SOp s3,
                                       iv4 (&acc)[8][4],
                                       int wm, int wn, int wid, int lane)
{
    const int l15 = lane & 15;
    const int c   = lane >> 4;
    iv4 a0[4], a1[4], b0[2], b1[2];

    // ---- P0: read a0+b0 (6 b128) | stage | MFMA q(0,0)
    read_a0(a0, tA, wm, l15, c);
    read_b0(b0, tB, wn, l15, c);
    if constexpr (S0) stage_half(s0, wid, lane);
    __builtin_amdgcn_s_barrier();
    __builtin_amdgcn_s_setprio(1);
    #pragma unroll
    for (int mi = 0; mi < 4; ++mi)
        #pragma unroll
        for (int ni = 0; ni < 2; ++ni)
            acc[mi][ni] = __builtin_amdgcn_mfma_i32_16x16x64_i8(
                a0[mi], b0[ni], acc[mi][ni], 0, 0, 0);
    __builtin_amdgcn_s_setprio(0);
    __builtin_amdgcn_s_barrier();

    // ---- P1: read b1 | stage | MFMA q(0,1)
    read_b1(b1, tB, wn, l15, c);
    if constexpr (S1) stage_half(s1, wid, lane);
    __builtin_amdgcn_s_barrier();
    __builtin_amdgcn_s_setprio(1);
    #pragma unroll
    for (int mi = 0; mi < 4; ++mi)
        #pragma unroll
        for (int ni = 0; ni < 2; ++ni)
            acc[mi][2 + ni] = __builtin_amdgcn_mfma_i32_16x16x64_i8(
                a0[mi], b1[ni], acc[mi][2 + ni], 0, 0, 0);
    __builtin_amdgcn_s_setprio(0);
    __builtin_amdgcn_s_barrier();

    // ---- P2: read a1 | stage | MFMA q(1,0)
    read_a1(a1, tA, wm, l15, c);
    if constexpr (S2) stage_half(s2, wid, lane);
    __builtin_amdgcn_s_barrier();
    __builtin_amdgcn_s_setprio(1);
    #pragma unroll
    for (int mi = 0; mi < 4; ++mi)
        #pragma unroll
        for (int ni = 0; ni < 2; ++ni)
            acc[4 + mi][ni] = __builtin_amdgcn_mfma_i32_16x16x64_i8(
                a1[mi], b0[ni], acc[4 + mi][ni], 0, 0, 0);
    __builtin_amdgcn_s_setprio(0);
    __builtin_amdgcn_s_barrier();

    // ---- P3: stage | MFMA q(1,1) | counted vmcnt | barrier
    if constexpr (S3) stage_half(s3, wid, lane);
    __builtin_amdgcn_s_barrier();
    __builtin_amdgcn_s_setprio(1);
    #pragma unroll
    for (int mi = 0; mi < 4; ++mi)
        #pragma unroll
        for (int ni = 0; ni < 2; ++ni)
            acc[4 + mi][2 + ni] = __builtin_amdgcn_mfma_i32_16x16x64_i8(
                a1[mi], b1[ni], acc[4 + mi][2 + ni], 0, 0, 0);
    __builtin_amdgcn_s_setprio(0);
    if constexpr (WN == 1)      asm volatile("s_waitcnt vmcnt(1)" ::: "memory");
    else if constexpr (WN == 0) asm volatile("s_waitcnt vmcnt(0)" ::: "memory");
    if constexpr (WN >= 0) __builtin_amdgcn_s_barrier();
}

__global__ __launch_bounds__(512, 2) void bitlinear_gemm_i8(
    const char* __restrict__ A, const char* __restrict__ B,
    const float* __restrict__ sx, const float* __restrict__ sw,
    float* __restrict__ C, int M)
{
    extern __shared__ char smem[];
    char* As0 = smem;            // [256][64B]
    char* As1 = smem + 16384;
    char* Bs0 = smem + 32768;
    char* Bs1 = smem + 49152;

    const int tid = threadIdx.x, lane = tid & 63, wid = tid >> 6;
    const int wm = wid >> 2, wn = wid & 3;

    // T1: bijective XCD swizzle (grid % 8 == 0 guaranteed by launcher)
    const int nbid = (int)blockIdx.x;
    const int cpx  = (int)gridDim.x >> 3;
    const int swz  = (nbid & 7) * cpx + (nbid >> 3);
    const int ntn  = N_DIM / 256;       // 16
    const int tm = swz / ntn, tn = swz % ntn;

    const char* gA = A + (long long)tm * 256 * K_DIM;
    const char* gB = B + (long long)tn * 256 * K_DIM;

    iv4 acc[8][4];
    #pragma unroll
    for (int i = 0; i < 8; ++i)
        #pragma unroll
        for (int j = 0; j < 4; ++j) acc[i][j] = (iv4){0, 0, 0, 0};

    // prologue: tile0 (4 halves) + Ah0(1) = 5 loads; vmcnt(1) drains tile0.
    stage_half({gA,   0,  0, As0},        wid, lane);
    stage_half({gA, 128,  0, As0 + 8192}, wid, lane);
    stage_half({gB,   0,  0, Bs0},        wid, lane);
    stage_half({gB, 128,  0, Bs0 + 8192}, wid, lane);
    stage_half({gA,   0, 64, As1},        wid, lane);
    asm volatile("s_waitcnt vmcnt(1)" ::: "memory");
    __builtin_amdgcn_s_barrier();

    // steady: stage Ah1(t+1)@P0, Bh0(t+1)@P1, Bh1(t+1)@P2, Ah0(t+2)@P3;
    // vmcnt(1) at P3-end drains exactly tile t+1 (4 loads), leaves Ah0(t+2).
    // t=0 (buf0)
    kgroup<true, true, true, true, 1>(As0, Bs0,
        {gA, 128,  64, As1 + 8192}, {gB, 0,  64, Bs1},
        {gB, 128,  64, Bs1 + 8192}, {gA, 0, 128, As0},
        acc, wm, wn, wid, lane);
    // t=1..60 in pairs (buf1, buf0)
    #pragma unroll 1
    for (int i = 0; i < 30; ++i) {
        const int kt = (2 * i + 1) * 64;
        kgroup<true, true, true, true, 1>(As1, Bs1,
            {gA, 128, kt + 64,  As0 + 8192}, {gB, 0, kt + 64,  Bs0},
            {gB, 128, kt + 64,  Bs0 + 8192}, {gA, 0, kt + 128, As1},
            acc, wm, wn, wid, lane);
        kgroup<true, true, true, true, 1>(As0, Bs0,
            {gA, 128, kt + 128, As1 + 8192}, {gB, 0, kt + 128, Bs1},
            {gB, 128, kt + 128, Bs1 + 8192}, {gA, 0, kt + 192, As0},
            acc, wm, wn, wid, lane);
    }
    // t=61 (buf1): full steady
    kgroup<true, true, true, true, 1>(As1, Bs1,
        {gA, 128, 62 * 64, As0 + 8192}, {gB, 0, 62 * 64, Bs0},
        {gB, 128, 62 * 64, Bs0 + 8192}, {gA, 0, 63 * 64, As1},
        acc, wm, wn, wid, lane);
    // t=62 (buf0): stage Ah1(63),Bh0(63),Bh1(63); drain all
    kgroup<true, true, true, false, 0>(As0, Bs0,
        {gA, 128, 63 * 64, As1 + 8192}, {gB, 0, 63 * 64, Bs1},
        {gB, 128, 63 * 64, Bs1 + 8192}, {gA, 0, 0, As0},
        acc, wm, wn, wid, lane);
    // t=63 (buf1): plain compute
    kgroup<false, false, false, false, -1>(As1, Bs1,
        {gA, 0, 0, As0}, {gA, 0, 0, As0}, {gA, 0, 0, As0}, {gA, 0, 0, As0},
        acc, wm, wn, wid, lane);

    // epilogue: out = i32 * sw[col] * sx[row].
    // C/D layout (dtype-independent, verified): col=lane&15, row=(lane>>4)*4+j
    const long long m0 = (long long)tm * 256 + wm * 128;
    const long long n0 = (long long)tn * 256 + wn * 64;
    float swv[4];
    #pragma unroll
    for (int ni = 0; ni < 4; ++ni) swv[ni] = sw[n0 + ni * 16 + (lane & 15)];
    #pragma unroll
    for (int mi = 0; mi < 8; ++mi) {
        const long long rowb = m0 + mi * 16 + (lane >> 4) * 4;
        float sxr[4];
        #pragma unroll
        for (int j = 0; j < 4; ++j) sxr[j] = sx[rowb + j];
        #pragma unroll
        for (int ni = 0; ni < 4; ++ni) {
            const long long col = n0 + ni * 16 + (lane & 15);
            #pragma unroll
            for (int j = 0; j < 4; ++j)
                C[(rowb + j) * N_DIM + col] = (float)acc[mi][ni][j] * swv[ni] * sxr[j];
        }
    }
}

// ---------------------------------------------------------------------------
// Naive fp32 fallback (shape/workspace escape hatch)
// ---------------------------------------------------------------------------
__global__ void bitlinear_naive_kernel(const float* __restrict__ x,
                                       const float* __restrict__ w,
                                       float* __restrict__ out, long long total) {
    const long long idx = (long long)blockIdx.x * blockDim.x + threadIdx.x;
    if (idx >= total) return;
    const long long m = idx / N_DIM;
    const long long o = idx % N_DIM;
    const float* xr = x + m * K_DIM;
    const float* wrow = w + o * K_DIM;
    float sum = 0.f, sa = 0.f;
    for (int k = 0; k < K_DIM; ++k) {
        float wv = wrow[k];
        sa += fabsf(wv);
        sum += xr[k] * ((wv > 0.f) ? 1.f : ((wv < 0.f) ? -1.f : 0.f));
    }
    out[idx] = sum * (sa * (1.0f / (float)K_DIM));
}

// ---------------------------------------------------------------------------
extern "C" void kernel_launch(void* const* d_in, const int* in_sizes, int n_in,
                              void* d_out, int out_size, void* d_ws, size_t ws_size,
                              hipStream_t stream) {
    const float* x = (const float*)d_in[0];   // [B,S,K] fp32
    const float* w = (const float*)d_in[1];   // [N,K] fp32
    float* out = (float*)d_out;               // [B,S,N] fp32

    const int M = in_sizes[0] / K_DIM;        // 8192

    const size_t xq_bytes = (size_t)M * K_DIM;
    const size_t wq_bytes = (size_t)N_DIM * K_DIM;
    const size_t sx_bytes = (size_t)M * sizeof(float);
    const size_t sw_bytes = (size_t)N_DIM * sizeof(float);

    if (ws_size < xq_bytes + wq_bytes + sx_bytes + sw_bytes || (M % 256) != 0) {
        const long long total = (long long)M * N_DIM;
        bitlinear_naive_kernel<<<(int)((total + 255) / 256), 256, 0, stream>>>(x, w, out, total);
        return;
    }

    char*  xq = (char*)d_ws;
    char*  wq = (char*)d_ws + xq_bytes;
    float* sx = (float*)((char*)d_ws + xq_bytes + wq_bytes);
    float* sw = (float*)((char*)d_ws + xq_bytes + wq_bytes + sx_bytes);

    convert_x_i8<<<M, 256, 0, stream>>>(x, xq, sx);
    convert_w_i8<<<N_DIM, 256, 0, stream>>>(w, wq, sw);

    // 64 KiB dynamic LDS (== device default max; attribute set defensively)
    hipFuncSetAttribute((const void*)bitlinear_gemm_i8,
                        hipFuncAttributeMaxDynamicSharedMemorySize, 65536);
    const int grid = (M / 256) * (N_DIM / 256);   // 32*16 = 512, %8==0
    bitlinear_gemm_i8<<<grid, 512, 65536, stream>>>(xq, wq, sx, sw, out, M);
}

// Round 7
// 182.876 us; speedup vs baseline: 1.5642x; 1.0137x over previous
//
#include <hip/hip_runtime.h>
#include <hip/hip_bf16.h>
#include <stdint.h>

typedef int  iv4   __attribute__((ext_vector_type(4)));   // 16 i8 operand / i32x4 acc
typedef float f32x4 __attribute__((ext_vector_type(4)));

#define K_DIM 4096
#define N_DIM 4096

// ---------------------------------------------------------------------------
// Kernel 1: x fp32 -> i8 with per-row scale sx[row] = rowmax/127.
// ---------------------------------------------------------------------------
__global__ __launch_bounds__(256) void convert_x_i8(const float* __restrict__ x,
                                                    char* __restrict__ xq,
                                                    float* __restrict__ sx) {
    const int row = blockIdx.x;
    const int tid = threadIdx.x;
    const float* xr = x + (long long)row * K_DIM + tid * 16;

    float4 v0 = *(const float4*)(xr + 0);
    float4 v1 = *(const float4*)(xr + 4);
    float4 v2 = *(const float4*)(xr + 8);
    float4 v3 = *(const float4*)(xr + 12);

    float m = fabsf(v0.x);
    m = fmaxf(m, fabsf(v0.y)); m = fmaxf(m, fabsf(v0.z)); m = fmaxf(m, fabsf(v0.w));
    m = fmaxf(m, fabsf(v1.x)); m = fmaxf(m, fabsf(v1.y)); m = fmaxf(m, fabsf(v1.z)); m = fmaxf(m, fabsf(v1.w));
    m = fmaxf(m, fabsf(v2.x)); m = fmaxf(m, fabsf(v2.y)); m = fmaxf(m, fabsf(v2.z)); m = fmaxf(m, fabsf(v2.w));
    m = fmaxf(m, fabsf(v3.x)); m = fmaxf(m, fabsf(v3.y)); m = fmaxf(m, fabsf(v3.z)); m = fmaxf(m, fabsf(v3.w));

    #pragma unroll
    for (int d = 32; d > 0; d >>= 1) m = fmaxf(m, __shfl_xor(m, d));
    __shared__ float red[4];
    const int lane = tid & 63, wid = tid >> 6;
    if (lane == 0) red[wid] = m;
    __syncthreads();
    float rmax = fmaxf(fmaxf(red[0], red[1]), fmaxf(red[2], red[3]));
    rmax = fmaxf(rmax, 1e-20f);
    if (tid == 0) sx[row] = rmax * (1.0f / 127.0f);

    const float q = 127.0f / rmax;
    union { char c[16]; int4 v; } u;
    const float vals[16] = {v0.x, v0.y, v0.z, v0.w, v1.x, v1.y, v1.z, v1.w,
                            v2.x, v2.y, v2.z, v2.w, v3.x, v3.y, v3.z, v3.w};
    #pragma unroll
    for (int i = 0; i < 16; ++i) u.c[i] = (char)__float2int_rn(vals[i] * q);
    *(int4*)(xq + (long long)row * K_DIM + tid * 16) = u.v;
}

// ---------------------------------------------------------------------------
// Kernel 2: weight row -> sign (i8, exact) + per-row mean|w| (fp32)
// ---------------------------------------------------------------------------
__global__ __launch_bounds__(256) void convert_w_i8(const float* __restrict__ w,
                                                    char* __restrict__ wq,
                                                    float* __restrict__ sw) {
    const int row = blockIdx.x;
    const int tid = threadIdx.x;
    const float* wr = w + (long long)row * K_DIM + tid * 16;

    float sum = 0.f;
    union { char c[16]; int4 v; } u;
    #pragma unroll
    for (int j = 0; j < 4; ++j) {
        float4 v = *(const float4*)(wr + j * 4);
        sum += fabsf(v.x) + fabsf(v.y) + fabsf(v.z) + fabsf(v.w);
        u.c[j * 4 + 0] = (char)((v.x > 0.f) - (v.x < 0.f));
        u.c[j * 4 + 1] = (char)((v.y > 0.f) - (v.y < 0.f));
        u.c[j * 4 + 2] = (char)((v.z > 0.f) - (v.z < 0.f));
        u.c[j * 4 + 3] = (char)((v.w > 0.f) - (v.w < 0.f));
    }
    *(int4*)(wq + (long long)row * K_DIM + tid * 16) = u.v;

    #pragma unroll
    for (int d = 32; d > 0; d >>= 1) sum += __shfl_down(sum, d);
    __shared__ float red[4];
    const int lane = tid & 63, wid = tid >> 6;
    if (lane == 0) red[wid] = sum;
    __syncthreads();
    if (tid == 0) sw[row] = (red[0] + red[1] + red[2] + red[3]) * (1.0f / (float)K_DIM);
}

// ===========================================================================
// 256x256 i8 GEMM, TRIPLE-buffered, frag reads ONE PHASE AHEAD of their MFMA:
//   P0: read b1(t)      | stage Ah0(t+2)->stg | q00(a0,b0)
//   P1: read a1(t)      | stage Ah1(t+2)->stg | q01(a0,b1)
//   P2: -               | stage Bh0(t+2)->stg | q10(a1,b0) ; vmcnt(3); bar
//   P3: read a0,b0(t+1) | stage Bh1(t+2)->stg | q11(a1,b1)
// Stage target is the always-idle 3rd buffer -> zero WAR exposure.
// FIFO (1 load per stage op): end-P2(t) outstanding =
//   {Bh1(t+1)@P3(t-1), Ah0(t+2)@P0, Ah1(t+2)@P1, Bh0(t+2)@P2} -> vmcnt(3)
//   drains exactly tile t+1; needed-newest had 3 phases (~900cy) to land.
// Tail: t=62 no-stage vmcnt(0); t=63 plain. LDS = 96 KiB -> 1 block/CU.
// Swizzle identical to round-6 (measured 0 conflicts).
// ===========================================================================
struct SOp { const char* g; int row0; int kt; char* l; };

__device__ __forceinline__ void stage_half(const SOp s, int wid, int lane) {
    const int r      = s.row0 + wid * 16 + (lane >> 2);
    const int srcoff = s.kt + ((((lane & 3) ^ ((lane >> 3) & 3))) << 4);
    const char* src  = s.g + (long long)r * K_DIM + srcoff;
    __builtin_amdgcn_global_load_lds(
        (const __attribute__((address_space(1))) void*)src,
        (__attribute__((address_space(3))) void*)(s.l + wid * 1024), 16, 0, 0);
}

__device__ __forceinline__ iv4 ldsr(const char* t, int row, int c) {
    const int off = row * 64 + ((c ^ ((row >> 1) & 3)) << 4);
    return *(const iv4*)(t + off);
}

__device__ __forceinline__ void read_a0(iv4 (&a)[4], const char* tA, int wm, int l15, int c) {
    #pragma unroll
    for (int mi = 0; mi < 4; ++mi) a[mi] = ldsr(tA, wm * 128 + mi * 16 + l15, c);
}
__device__ __forceinline__ void read_a1(iv4 (&a)[4], const char* tA, int wm, int l15, int c) {
    #pragma unroll
    for (int mi = 0; mi < 4; ++mi) a[mi] = ldsr(tA, wm * 128 + 64 + mi * 16 + l15, c);
}
__device__ __forceinline__ void read_b0(iv4 (&b)[2], const char* tB, int wn, int l15, int c) {
    #pragma unroll
    for (int ni = 0; ni < 2; ++ni) b[ni] = ldsr(tB, wn * 64 + ni * 16 + l15, c);
}
__device__ __forceinline__ void read_b1(iv4 (&b)[2], const char* tB, int wn, int l15, int c) {
    #pragma unroll
    for (int ni = 0; ni < 2; ++ni) b[ni] = ldsr(tB, wn * 64 + 32 + ni * 16 + l15, c);
}

// ST: stage tile t+2 into sA/sB. WN: 3 steady / 0 drain / -1 none.
// RA: read a0,b0(t+1) from oA/oB at P3.
template<bool ST, int WN, bool RA>
__device__ __forceinline__ void ktile(const char* __restrict__ cA,
                                      const char* __restrict__ cB,
                                      const char* __restrict__ oA,
                                      const char* __restrict__ oB,
                                      char* __restrict__ sA,
                                      char* __restrict__ sB,
                                      const char* gA, const char* gB, int kt2,
                                      iv4 (&a0)[4], iv4 (&b0)[2],
                                      iv4 (&acc)[8][4],
                                      int wm, int wn, int wid, int lane)
{
    const int l15 = lane & 15;
    const int c   = lane >> 4;
    iv4 a1[4], b1[2];

    // ---- P0: read b1(t) | stage Ah0(t+2) | MFMA q00 (a0,b0)
    read_b1(b1, cB, wn, l15, c);
    if constexpr (ST) stage_half({gA, 0, kt2, sA}, wid, lane);
    __builtin_amdgcn_s_barrier();
    __builtin_amdgcn_s_setprio(1);
    #pragma unroll
    for (int mi = 0; mi < 4; ++mi)
        #pragma unroll
        for (int ni = 0; ni < 2; ++ni)
            acc[mi][ni] = __builtin_amdgcn_mfma_i32_16x16x64_i8(
                a0[mi], b0[ni], acc[mi][ni], 0, 0, 0);
    __builtin_amdgcn_s_setprio(0);
    __builtin_amdgcn_s_barrier();

    // ---- P1: read a1(t) | stage Ah1(t+2) | MFMA q01 (a0,b1)
    read_a1(a1, cA, wm, l15, c);
    if constexpr (ST) stage_half({gA, 128, kt2, sA + 8192}, wid, lane);
    __builtin_amdgcn_s_barrier();
    __builtin_amdgcn_s_setprio(1);
    #pragma unroll
    for (int mi = 0; mi < 4; ++mi)
        #pragma unroll
        for (int ni = 0; ni < 2; ++ni)
            acc[mi][2 + ni] = __builtin_amdgcn_mfma_i32_16x16x64_i8(
                a0[mi], b1[ni], acc[mi][2 + ni], 0, 0, 0);
    __builtin_amdgcn_s_setprio(0);
    __builtin_amdgcn_s_barrier();

    // ---- P2: stage Bh0(t+2) | MFMA q10 (a1,b0) | vmcnt -> tile t+1 landed
    if constexpr (ST) stage_half({gB, 0, kt2, sB}, wid, lane);
    __builtin_amdgcn_s_barrier();
    __builtin_amdgcn_s_setprio(1);
    #pragma unroll
    for (int mi = 0; mi < 4; ++mi)
        #pragma unroll
        for (int ni = 0; ni < 2; ++ni)
            acc[4 + mi][ni] = __builtin_amdgcn_mfma_i32_16x16x64_i8(
                a1[mi], b0[ni], acc[4 + mi][ni], 0, 0, 0);
    __builtin_amdgcn_s_setprio(0);
    if constexpr (WN == 3)      asm volatile("s_waitcnt vmcnt(3)" ::: "memory");
    else if constexpr (WN == 0) asm volatile("s_waitcnt vmcnt(0)" ::: "memory");
    __builtin_amdgcn_s_barrier();
    if constexpr (RA) __builtin_amdgcn_sched_barrier(0);

    // ---- P3: read a0,b0(t+1) from other buf | stage Bh1(t+2) | MFMA q11 (a1,b1)
    if constexpr (RA) {
        read_a0(a0, oA, wm, l15, c);
        read_b0(b0, oB, wn, l15, c);
    }
    if constexpr (ST) stage_half({gB, 128, kt2, sB + 8192}, wid, lane);
    __builtin_amdgcn_s_barrier();
    __builtin_amdgcn_s_setprio(1);
    #pragma unroll
    for (int mi = 0; mi < 4; ++mi)
        #pragma unroll
        for (int ni = 0; ni < 2; ++ni)
            acc[4 + mi][2 + ni] = __builtin_amdgcn_mfma_i32_16x16x64_i8(
                a1[mi], b1[ni], acc[4 + mi][2 + ni], 0, 0, 0);
    __builtin_amdgcn_s_setprio(0);
    __builtin_amdgcn_s_barrier();
}

__global__ __launch_bounds__(512, 2) void bitlinear_gemm_i8(
    const char* __restrict__ A, const char* __restrict__ B,
    const float* __restrict__ sx, const float* __restrict__ sw,
    float* __restrict__ C, int M)
{
    extern __shared__ char smem[];
    char* As0 = smem;
    char* As1 = smem + 16384;
    char* As2 = smem + 32768;
    char* Bs0 = smem + 49152;
    char* Bs1 = smem + 65536;
    char* Bs2 = smem + 81920;

    const int tid = threadIdx.x, lane = tid & 63, wid = tid >> 6;
    const int wm = wid >> 2, wn = wid & 3;
    const int l15 = lane & 15;
    const int c   = lane >> 4;

    // T1: bijective XCD swizzle (grid % 8 == 0 guaranteed by launcher)
    const int nbid = (int)blockIdx.x;
    const int cpx  = (int)gridDim.x >> 3;
    const int swz  = (nbid & 7) * cpx + (nbid >> 3);
    const int ntn  = N_DIM / 256;       // 16
    const int tm = swz / ntn, tn = swz % ntn;

    const char* gA = A + (long long)tm * 256 * K_DIM;
    const char* gB = B + (long long)tn * 256 * K_DIM;

    iv4 acc[8][4];
    #pragma unroll
    for (int i = 0; i < 8; ++i)
        #pragma unroll
        for (int j = 0; j < 4; ++j) acc[i][j] = (iv4){0, 0, 0, 0};

    // prologue: stage t0 -> buf0, t1 -> buf1 (8 loads); vmcnt(4) drains t0.
    stage_half({gA,   0,   0, As0},        wid, lane);
    stage_half({gA, 128,   0, As0 + 8192}, wid, lane);
    stage_half({gB,   0,   0, Bs0},        wid, lane);
    stage_half({gB, 128,   0, Bs0 + 8192}, wid, lane);
    stage_half({gA,   0,  64, As1},        wid, lane);
    stage_half({gA, 128,  64, As1 + 8192}, wid, lane);
    stage_half({gB,   0,  64, Bs1},        wid, lane);
    stage_half({gB, 128,  64, Bs1 + 8192}, wid, lane);
    asm volatile("s_waitcnt vmcnt(4)" ::: "memory");
    __builtin_amdgcn_s_barrier();
    __builtin_amdgcn_sched_barrier(0);

    iv4 a0[4], b0[2];
    read_a0(a0, As0, wm, l15, c);
    read_b0(b0, Bs0, wn, l15, c);

    // t = 0..59 (20 x 3 rotations), all steady
    #pragma unroll 1
    for (int i = 0; i < 20; ++i) {
        const int t = 3 * i;
        ktile<true, 3, true>(As0, Bs0, As1, Bs1, As2, Bs2,
                             gA, gB, (t + 2) * 64, a0, b0, acc, wm, wn, wid, lane);
        ktile<true, 3, true>(As1, Bs1, As2, Bs2, As0, Bs0,
                             gA, gB, (t + 3) * 64, a0, b0, acc, wm, wn, wid, lane);
        ktile<true, 3, true>(As2, Bs2, As0, Bs0, As1, Bs1,
                             gA, gB, (t + 4) * 64, a0, b0, acc, wm, wn, wid, lane);
    }
    // t=60 (stages t62), t=61 (stages t63)
    ktile<true, 3, true>(As0, Bs0, As1, Bs1, As2, Bs2,
                         gA, gB, 62 * 64, a0, b0, acc, wm, wn, wid, lane);
    ktile<true, 3, true>(As1, Bs1, As2, Bs2, As0, Bs0,
                         gA, gB, 63 * 64, a0, b0, acc, wm, wn, wid, lane);
    // t=62: no stages; vmcnt(0) drains t63; read-ahead t63 from buf0
    ktile<false, 0, true>(As2, Bs2, As0, Bs0, As1, Bs1,
                          gA, gB, 0, a0, b0, acc, wm, wn, wid, lane);
    // t=63: plain compute
    ktile<false, -1, false>(As0, Bs0, As1, Bs1, As2, Bs2,
                            gA, gB, 0, a0, b0, acc, wm, wn, wid, lane);

    // epilogue: out = i32 * sw[col] * sx[row]. C/D: col=lane&15, row=(lane>>4)*4+j
    const long long m0 = (long long)tm * 256 + wm * 128;
    const long long n0 = (long long)tn * 256 + wn * 64;
    float swv[4];
    #pragma unroll
    for (int ni = 0; ni < 4; ++ni) swv[ni] = sw[n0 + ni * 16 + (lane & 15)];
    #pragma unroll
    for (int mi = 0; mi < 8; ++mi) {
        const long long rowb = m0 + mi * 16 + (lane >> 4) * 4;
        float sxr[4];
        #pragma unroll
        for (int j = 0; j < 4; ++j) sxr[j] = sx[rowb + j];
        #pragma unroll
        for (int ni = 0; ni < 4; ++ni) {
            const long long col = n0 + ni * 16 + (lane & 15);
            #pragma unroll
            for (int j = 0; j < 4; ++j)
                C[(rowb + j) * N_DIM + col] = (float)acc[mi][ni][j] * swv[ni] * sxr[j];
        }
    }
}

// ---------------------------------------------------------------------------
// Naive fp32 fallback (shape/workspace escape hatch)
// ---------------------------------------------------------------------------
__global__ void bitlinear_naive_kernel(const float* __restrict__ x,
                                       const float* __restrict__ w,
                                       float* __restrict__ out, long long total) {
    const long long idx = (long long)blockIdx.x * blockDim.x + threadIdx.x;
    if (idx >= total) return;
    const long long m = idx / N_DIM;
    const long long o = idx % N_DIM;
    const float* xr = x + m * K_DIM;
    const float* wrow = w + o * K_DIM;
    float sum = 0.f, sa = 0.f;
    for (int k = 0; k < K_DIM; ++k) {
        float wv = wrow[k];
        sa += fabsf(wv);
        sum += xr[k] * ((wv > 0.f) ? 1.f : ((wv < 0.f) ? -1.f : 0.f));
    }
    out[idx] = sum * (sa * (1.0f / (float)K_DIM));
}

// ---------------------------------------------------------------------------
extern "C" void kernel_launch(void* const* d_in, const int* in_sizes, int n_in,
                              void* d_out, int out_size, void* d_ws, size_t ws_size,
                              hipStream_t stream) {
    const float* x = (const float*)d_in[0];   // [B,S,K] fp32
    const float* w = (const float*)d_in[1];   // [N,K] fp32
    float* out = (float*)d_out;               // [B,S,N] fp32

    const int M = in_sizes[0] / K_DIM;        // 8192

    const size_t xq_bytes = (size_t)M * K_DIM;
    const size_t wq_bytes = (size_t)N_DIM * K_DIM;
    const size_t sx_bytes = (size_t)M * sizeof(float);
    const size_t sw_bytes = (size_t)N_DIM * sizeof(float);

    if (ws_size < xq_bytes + wq_bytes + sx_bytes + sw_bytes || (M % 256) != 0) {
        const long long total = (long long)M * N_DIM;
        bitlinear_naive_kernel<<<(int)((total + 255) / 256), 256, 0, stream>>>(x, w, out, total);
        return;
    }

    char*  xq = (char*)d_ws;
    char*  wq = (char*)d_ws + xq_bytes;
    float* sx = (float*)((char*)d_ws + xq_bytes + wq_bytes);
    float* sw = (float*)((char*)d_ws + xq_bytes + wq_bytes + sx_bytes);

    convert_x_i8<<<M, 256, 0, stream>>>(x, xq, sx);
    convert_w_i8<<<N_DIM, 256, 0, stream>>>(w, wq, sw);

    hipFuncSetAttribute((const void*)bitlinear_gemm_i8,
                        hipFuncAttributeMaxDynamicSharedMemorySize, 98304);
    const int grid = (M / 256) * (N_DIM / 256);   // 32*16 = 512, %8==0
    bitlinear_gemm_i8<<<grid, 512, 98304, stream>>>(xq, wq, sx, sw, out, M);
}